// Round 8
// baseline (752.789 us; speedup 1.0000x reference)
//
#include <hip/hip_runtime.h>
#include <hip/hip_cooperative_groups.h>
#include <math.h>
#include <stdint.h>

namespace cg = cooperative_groups;

#define DI __device__ __forceinline__

typedef __attribute__((ext_vector_type(8))) short bf16x8;
typedef __attribute__((ext_vector_type(4))) float f32x4;
typedef __attribute__((ext_vector_type(4))) int i32x4;

DI float elu_f(float v) { return v > 0.f ? v : expm1f(v); }

DI unsigned short f2bf(float f) {  // fp32 -> bf16 RNE
  uint32_t u = __float_as_uint(f);
  return (unsigned short)((u + 0x7FFFu + ((u >> 16) & 1u)) >> 16);
}

// ---------------- threefry2x32 (JAX, 20 rounds)
DI void threefry2x32(uint32_t k0, uint32_t k1, uint32_t& x0, uint32_t& x1) {
  uint32_t ks0 = k0, ks1 = k1, ks2 = k0 ^ k1 ^ 0x1BD11BDAu;
  x0 += ks0; x1 += ks1;
#define TFR(r) { x0 += x1; x1 = (x1 << r) | (x1 >> (32 - r)); x1 ^= x0; }
  TFR(13) TFR(15) TFR(26) TFR(6)   x0 += ks1; x1 += ks2 + 1u;
  TFR(17) TFR(29) TFR(16) TFR(24)  x0 += ks2; x1 += ks0 + 2u;
  TFR(13) TFR(15) TFR(26) TFR(6)   x0 += ks0; x1 += ks1 + 3u;
  TFR(17) TFR(29) TFR(16) TFR(24)  x0 += ks1; x1 += ks2 + 4u;
  TFR(13) TFR(15) TFR(26) TFR(6)   x0 += ks2; x1 += ks0 + 5u;
#undef TFR
}

DI float erfinv_f(float x) {  // Giles erfinv (rel err ~1e-6 << bf16 quantum)
  float w = -logf((1.0f - x) * (1.0f + x));
  float p;
  if (w < 5.0f) {
    w -= 2.5f;
    p = 2.81022636e-08f;
    p = fmaf(p, w, 3.43273939e-07f);
    p = fmaf(p, w, -3.5233877e-06f);
    p = fmaf(p, w, -4.39150654e-06f);
    p = fmaf(p, w, 0.00021858087f);
    p = fmaf(p, w, -0.00125372503f);
    p = fmaf(p, w, -0.00417768164f);
    p = fmaf(p, w, 0.246640727f);
    p = fmaf(p, w, 1.50140941f);
  } else {
    w = sqrtf(w) - 3.0f;
    p = -0.000200214257f;
    p = fmaf(p, w, 0.000100950558f);
    p = fmaf(p, w, 0.00134934322f);
    p = fmaf(p, w, -0.00367342844f);
    p = fmaf(p, w, 0.00573950773f);
    p = fmaf(p, w, -0.0076224613f);
    p = fmaf(p, w, 0.00943887047f);
    p = fmaf(p, w, 1.00167406f);
    p = fmaf(p, w, 2.83297682f);
  }
  return p * x;
}

struct MegaArgs {
  const float *x, *c;
  const float *fc1w, *fc1b, *fc2w, *fc2b, *muw, *mub, *lvw, *lvb;
  const float *g0w, *g0b, *g1w, *g1b, *g2w, *g2b;
  const float *w0, *b0, *w1, *b1, *w2, *b2;
  unsigned short *Ax, *Axh, *Axh2, *A0, *A1, *A2;
  unsigned short *fc1t, *fc2t, *mlvt, *g0t, *g1t, *w0b, *w1b, *w2b;
  float *cf, *outY, *outMu, *outLv;
};

// =====================================================================
// phase_pipe: one 32r x 16c tile, 128 thr = 2 waves (wave w = rows w*16..+16).
// A-frags direct global->VGPR, W via register ring. LDS only bias/coeff.
template <int KT, int NE, int D, bool ELU, bool OUTF32>
DI void phase_pipe(unsigned char* SM, int tid, int tileIdx,
                   const unsigned short* __restrict__ A,
                   const unsigned short* __restrict__ Wt, int N,
                   const float* __restrict__ bias, const float* __restrict__ cfp,
                   unsigned short* __restrict__ Cb, int ldcb, int cb_off,
                   float* __restrict__ Cf) {
  constexpr int Kp = KT * 32, TT = NE * KT;
  float* bias_s = (float*)SM;            // NE*16 floats
  float* cfs = (float*)(SM + 512);       // 256 floats
  const int lane = tid & 63, wid = tid >> 6;
  const int q = lane >> 4, l16 = lane & 15;
  const int m0 = (tileIdx & 63) * 32, n0 = (tileIdx >> 6) * 16;
  const int gc = n0 + l16;
  const int wrow = (gc < N) ? gc : (N - 1);
  const unsigned short* wlane = Wt + (size_t)wrow * Kp + q * 8;
  const unsigned short* alane = A + (size_t)(m0 + wid * 16 + l16) * Kp + q * 8;

  __syncthreads();  // SM reuse safety across phases / repeated calls

  bf16x8 ring[D];
#pragma unroll
  for (int g = 0; g < D; g++) {
    if (g < TT) {
      int e = g / KT, c = g % KT;
      ring[g] = *(const bf16x8*)(wlane + (size_t)e * N * Kp + c * 32);
    }
  }
  bf16x8 areg[KT];
#pragma unroll
  for (int c = 0; c < KT; c++) areg[c] = *(const bf16x8*)(alane + c * 32);

  if (NE == 1) {
    if (tid < 16) bias_s[tid] = (n0 + tid < N) ? bias[n0 + tid] : 0.f;
  } else {
    if (tid < NE * 16) {
      int e = tid >> 4, col = tid & 15;
      bias_s[tid] = (n0 + col < N) ? bias[(size_t)e * N + n0 + col] : 0.f;
    }
    for (int idx = tid; idx < 256; idx += 128)
      cfs[idx] = cfp[(size_t)(m0 + (idx >> 3)) * 8 + (idx & 7)];
  }
  __syncthreads();

  f32x4 acc = {0.f, 0.f, 0.f, 0.f}, accF = {0.f, 0.f, 0.f, 0.f};
#pragma unroll
  for (int g = 0; g < TT; g++) {
    const int e = g / KT, c = g % KT;
    acc = __builtin_amdgcn_mfma_f32_16x16x32_bf16(areg[c], ring[g % D], acc, 0, 0, 0);
    if (g + D < TT) {
      int e2 = (g + D) / KT, c2 = (g + D) % KT;
      ring[g % D] = *(const bf16x8*)(wlane + (size_t)e2 * N * Kp + c2 * 32);
    }
    if (NE > 1 && c == KT - 1) {  // expert boundary: exact fp32 fold
      float bv2 = bias_s[e * 16 + l16];
#pragma unroll
      for (int r = 0; r < 4; r++) {
        float ce = cfs[(wid * 16 + q * 4 + r) * 8 + e];
        accF[r] += ce * (acc[r] + bv2);
        acc[r] = 0.f;
      }
    }
  }

  if (gc < N) {
#pragma unroll
    for (int r = 0; r < 4; r++) {
      int row = m0 + wid * 16 + q * 4 + r;
      float v = (NE > 1) ? accF[r] : (acc[r] + bias_s[l16]);
      if (ELU) v = elu_f(v);
      if (OUTF32) Cf[(size_t)row * 267 + gc] = v;
      else Cb[(size_t)row * ldcb + cb_off + gc] = f2bf(v);
    }
  }
}

// =====================================================================
// mulv+z+gate phase, 128 threads, blocks 0..127 (16 rows each)
DI void phase_mulv_gate(const MegaArgs& a, unsigned char* SM, int tid, int bid) {
  if (bid >= 128) return;
  float* mlvS = (float*)SM;                              // [16][65]
  unsigned short* A0p = (unsigned short*)(SM + 4160);    // [16][328]
  unsigned short* gaB = (unsigned short*)(SM + 14656);   // [16][72]
  unsigned short* g1B = (unsigned short*)(SM + 16960);   // [64][72]
  float* g2wT = (float*)(SM + 26176);                    // [64][8]
  float* gB = (float*)(SM + 28224);                      // [16][65]
  float* lg = (float*)(SM + 32384);                      // [16][8]
  const int lane = tid & 63, wid = tid >> 6;  // wid 0,1
  const int q = lane >> 4, l16 = lane & 15;
  const int m0 = bid * 16;

  // stage A0p c-part (cols 32..319) + pad, g1B, g2wT
  for (int idx = tid; idx < 16 * 36; idx += 128) {
    int row = idx / 36, ch = 4 + idx % 36;
    *(i32x4*)(A0p + row * 328 + ch * 8) =
        *(const i32x4*)(a.A0 + (size_t)(m0 + row) * 320 + ch * 8);
  }
  if (tid < 16) { i32x4 z4 = {0, 0, 0, 0}; *(i32x4*)(A0p + tid * 328 + 320) = z4; }
  for (int idx = tid; idx < 512; idx += 128) {
    int row = idx >> 3, ch = idx & 7;
    *(i32x4*)(g1B + row * 72 + ch * 8) = *(const i32x4*)(a.g1t + (size_t)row * 64 + ch * 8);
  }
  for (int idx = tid; idx < 512; idx += 128)
    g2wT[(idx & 63) * 8 + (idx >> 6)] = a.g2w[idx];

  // ---- phase A: mu/lv GEMM (16 rows x 64 cols; wave handles 2 col-tiles) ----
  const unsigned short* alane = a.Axh2 + (size_t)(m0 + l16) * 544 + q * 8;
  bf16x8 areg[17];
#pragma unroll
  for (int c = 0; c < 17; c++) areg[c] = *(const bf16x8*)(alane + c * 32);
#pragma unroll
  for (int c2 = 0; c2 < 2; c2++) {
    const int cl = wid * 32 + c2 * 16 + l16;
    const unsigned short* wl = a.mlvt + (size_t)cl * 544 + q * 8;
    bf16x8 ring[8];
#pragma unroll
    for (int g = 0; g < 8; g++) ring[g] = *(const bf16x8*)(wl + g * 32);
    f32x4 acc = {0.f, 0.f, 0.f, 0.f};
#pragma unroll
    for (int g = 0; g < 17; g++) {
      acc = __builtin_amdgcn_mfma_f32_16x16x32_bf16(areg[g], ring[g % 8], acc, 0, 0, 0);
      if (g + 8 < 17) ring[g % 8] = *(const bf16x8*)(wl + (g + 8) * 32);
    }
#pragma unroll
    for (int r = 0; r < 4; r++) mlvS[(q * 4 + r) * 65 + cl] = acc[r];
  }
  __syncthreads();

  // ---- phase B: z = mu + eps*exp(0.5*lv) (exact JAX threefry-normal) ----
  {
    const int m = tid >> 3, j0 = (tid & 7) * 4, R = m0 + m;
#pragma unroll
    for (int jj = 0; jj < 4; jj++) {
      int j = j0 + jj;
      float mu = mlvS[m * 65 + j] + a.mub[j];
      float lvv = mlvS[m * 65 + j + 32] + a.lvb[j];
      uint32_t x0 = 0u, x1 = (uint32_t)(R * 32 + j);
      threefry2x32(0u, 42u, x0, x1);
      uint32_t bits = x0 ^ x1;
      float f = __uint_as_float((bits >> 9) | 0x3F800000u) - 1.0f;
      const float lo = -0.99999994039535522461f;
      float u = fmaf(f, 2.0f, lo);
      u = fmaxf(u, lo);
      float eps = 1.41421356237f * erfinv_f(u);
      float z = fmaf(eps, expf(0.5f * lvv), mu);
      a.outMu[(size_t)R * 32 + j] = mu;
      a.outLv[(size_t)R * 32 + j] = lvv;
      unsigned short zb = f2bf(z);
      A0p[m * 328 + j] = zb;
      a.A0[(size_t)R * 320 + j] = zb;
      a.A1[(size_t)R * 288 + j] = zb;
      a.A2[(size_t)R * 288 + j] = zb;
    }
  }
  __syncthreads();

  // ---- phase C: g0 (A from LDS A0p, W ring) ----
#pragma unroll
  for (int c2 = 0; c2 < 2; c2++) {
    const int cl = wid * 32 + c2 * 16 + l16;
    const unsigned short* wl = a.g0t + (size_t)cl * 320 + q * 8;
    bf16x8 ring2[8];
#pragma unroll
    for (int g = 0; g < 8; g++) ring2[g] = *(const bf16x8*)(wl + g * 32);
    f32x4 accC = {0.f, 0.f, 0.f, 0.f};
#pragma unroll
    for (int g = 0; g < 10; g++) {
      bf16x8 av = *(const bf16x8*)(A0p + l16 * 328 + g * 32 + q * 8);
      accC = __builtin_amdgcn_mfma_f32_16x16x32_bf16(av, ring2[g % 8], accC, 0, 0, 0);
      if (g + 8 < 10) ring2[g % 8] = *(const bf16x8*)(wl + (g + 8) * 32);
    }
    float bc = a.g0b[cl];
#pragma unroll
    for (int r = 0; r < 4; r++)
      gaB[(q * 4 + r) * 72 + cl] = f2bf(elu_f(accC[r] + bc));
  }
  __syncthreads();

  // ---- phase D: g1 ----
#pragma unroll
  for (int c2 = 0; c2 < 2; c2++) {
    const int cl = wid * 32 + c2 * 16 + l16;
    f32x4 accD = {0.f, 0.f, 0.f, 0.f};
#pragma unroll
    for (int tau = 0; tau < 2; tau++) {
      bf16x8 av = *(const bf16x8*)(gaB + l16 * 72 + tau * 32 + q * 8);
      bf16x8 bv = *(const bf16x8*)(g1B + cl * 72 + tau * 32 + q * 8);
      accD = __builtin_amdgcn_mfma_f32_16x16x32_bf16(av, bv, accD, 0, 0, 0);
    }
    float bc = a.g1b[cl];
#pragma unroll
    for (int r = 0; r < 4; r++)
      gB[(q * 4 + r) * 65 + cl] = elu_f(accD[r] + bc);
  }
  __syncthreads();

  // ---- phase E: g2 logits + softmax -> cf ----
  {
    int r = tid >> 3, e = tid & 7;
    float d = a.g2b[e];
#pragma unroll 8
    for (int k = 0; k < 64; k++) d = fmaf(gB[r * 65 + k], g2wT[k * 8 + e], d);
    lg[r * 8 + e] = d;
  }
  __syncthreads();
  if (tid < 16) {
    float mx = lg[tid * 8];
#pragma unroll
    for (int e2 = 1; e2 < 8; e2++) mx = fmaxf(mx, lg[tid * 8 + e2]);
    float s = 0.f, ex[8];
#pragma unroll
    for (int e2 = 0; e2 < 8; e2++) { ex[e2] = expf(lg[tid * 8 + e2] - mx); s += ex[e2]; }
    float inv = 1.f / s;
#pragma unroll
    for (int e2 = 0; e2 < 8; e2++) a.cf[(size_t)(m0 + tid) * 8 + e2] = ex[e2] * inv;
  }
}

// =====================================================================
// MEGA: 1024 blocks x 128 thr cooperative — all GEMM phases, 5 grid syncs
__global__ __launch_bounds__(128, 2) void mega_kernel(MegaArgs a) {
  __shared__ __align__(16) unsigned char SM[33024];
  const int tid = threadIdx.x, bid = blockIdx.x;
  cg::grid_group grid = cg::this_grid();
  phase_pipe<17, 1, 12, true, false>(SM, tid, bid, a.Ax, a.fc1t, 256, a.fc1b,
                                     nullptr, a.Axh, 544, 267, nullptr);
  grid.sync();
  phase_pipe<17, 1, 12, true, false>(SM, tid, bid, a.Axh, a.fc2t, 256, a.fc2b,
                                     nullptr, a.Axh2, 544, 267, nullptr);
  grid.sync();
  phase_mulv_gate(a, SM, tid, bid);
  grid.sync();
  phase_pipe<10, 8, 16, true, false>(SM, tid, bid, a.A0, a.w0b, 256, a.b0,
                                     a.cf, a.A1, 288, 32, nullptr);
  grid.sync();
  phase_pipe<9, 8, 16, true, false>(SM, tid, bid, a.A1, a.w1b, 256, a.b1,
                                    a.cf, a.A2, 288, 32, nullptr);
  grid.sync();
  for (int t = bid; t < 64 * 17; t += 1024)
    phase_pipe<9, 8, 16, false, true>(SM, tid, t, a.A2, a.w2b, 267, a.b2,
                                      a.cf, nullptr, 0, 0, a.outY);
}

// =====================================================================
// prep (one dispatch, 1673 blocks x 256 thr) — unchanged (verified R5-R7)
__global__ __launch_bounds__(256) void k_prep(MegaArgs a) {
  __shared__ __align__(16) unsigned short T[64][72];
  const int bb = blockIdx.x, tid = threadIdx.x;
  if (bb < 512) {
    for (int rr = 0; rr < 4; rr++) {
      int b = bb * 4 + rr;
      const float* xr = a.x + (size_t)b * 267;
      const float* cr = a.c + (size_t)b * 267;
      unsigned short* axr = a.Ax + (size_t)b * 544;
      for (int k = tid; k < 544; k += 256) {
        float v = (k < 267) ? xr[k] : ((k < 534) ? cr[k - 267] : 0.f);
        axr[k] = f2bf(v);
      }
      unsigned short* ahr = a.Axh + (size_t)b * 544;
      unsigned short* ah2 = a.Axh2 + (size_t)b * 544;
      for (int k = tid; k < 267; k += 256) { unsigned short v = f2bf(xr[k]); ahr[k] = v; ah2[k] = v; }
      for (int k = 523 + tid; k < 544; k += 256) { ahr[k] = 0; ah2[k] = 0; }
      unsigned short* a0r = a.A0 + (size_t)b * 320;
      for (int k = tid; k < 288; k += 256)
        a0r[32 + k] = (k < 267) ? f2bf(cr[k]) : (unsigned short)0;
    }
  } else if (bb < 1152) {
    int r = bb - 512;
    const float* src; unsigned short* dst; int Ks, Kp2;
    if (r < 256)      { src = a.fc1w + (size_t)r * 534; dst = a.fc1t + (size_t)r * 544; Ks = 534; Kp2 = 544; }
    else if (r < 512) { int n = r - 256; src = a.fc2w + (size_t)n * 523; dst = a.fc2t + (size_t)n * 544; Ks = 523; Kp2 = 544; }
    else if (r < 576) { int n = r - 512; src = (n < 32) ? (a.muw + (size_t)n * 523) : (a.lvw + (size_t)(n - 32) * 523);
                        dst = a.mlvt + (size_t)n * 544; Ks = 523; Kp2 = 544; }
    else              { int n = r - 576; src = a.g0w + (size_t)n * 299; dst = a.g0t + (size_t)n * 320; Ks = 299; Kp2 = 320; }
    for (int k = tid; k < Kp2; k += 256) dst[k] = (k < Ks) ? f2bf(src[k]) : (unsigned short)0;
  } else if (bb == 1152) {
    for (int k = tid; k < 4096; k += 256) a.g1t[k] = f2bf(a.g1w[k]);
  } else {
    int t = bb - 1153;
    const float* W; unsigned short* D; int K, N2, Kp2, ldW, e, kt, nt;
    if (t < 160)      { e = t / 20;  int lt = t % 20;  kt = lt / 4; nt = lt % 4; W = a.w0; D = a.w0b; K = 299; N2 = 256; Kp2 = 320; ldW = 256; }
    else if (t < 320) { int u = t - 160; e = u / 20; int lt = u % 20; kt = lt / 4; nt = lt % 4; W = a.w1; D = a.w1b; K = 288; N2 = 256; Kp2 = 288; ldW = 256; }
    else              { int u = t - 320; e = u / 25; int lt = u % 25; kt = lt / 5; nt = lt % 5; W = a.w2; D = a.w2b; K = 288; N2 = 267; Kp2 = 288; ldW = 267; }
    const int k0 = kt * 64, n0 = nt * 64;
    const float* We = W + (size_t)e * K * ldW;
    const int jj = tid & 63, ii0 = tid >> 6;
#pragma unroll
    for (int p = 0; p < 16; p++) {
      int i = ii0 + p * 4;
      int gk = k0 + i, gn = n0 + jj;
      float v = (gk < K && gn < N2) ? We[(size_t)gk * ldW + gn] : 0.f;
      T[jj][i] = f2bf(v);
    }
    __syncthreads();
    int j = tid >> 2, chb = tid & 3;
    int gn = n0 + j;
    if (gn < N2) {
      unsigned short* drow = D + ((size_t)e * N2 + gn) * Kp2 + k0;
#pragma unroll
      for (int s = 0; s < 2; s++) {
        int ch = chb + s * 4;
        if (k0 + ch * 8 < Kp2) {
          i32x4 v = *(i32x4*)(&T[j][ch * 8]);
          *(i32x4*)(drow + ch * 8) = v;
        }
      }
    }
  }
}

// =====================================================================
// Fallback path (R7 structure): pipe16 + 256-thr mulv_gate
template <int KT, int NE, int D, bool ELU, bool OUTF32>
__global__ __launch_bounds__(128, 2)
void pipe16(const unsigned short* __restrict__ A,
            const unsigned short* __restrict__ Wt, int N,
            const float* __restrict__ bias, const float* __restrict__ cfp,
            unsigned short* __restrict__ Cb, int ldcb, int cb_off,
            float* __restrict__ Cf) {
  __shared__ __align__(16) unsigned char SM[2048];
  phase_pipe<KT, NE, D, ELU, OUTF32>(SM, threadIdx.x,
                                     blockIdx.x + (blockIdx.y << 6),
                                     A, Wt, N, bias, cfp, Cb, ldcb, cb_off, Cf);
}

__global__ __launch_bounds__(128, 2) void k_mulv_gate_fb(MegaArgs a) {
  __shared__ __align__(16) unsigned char SM[33024];
  phase_mulv_gate(a, SM, threadIdx.x, blockIdx.x);
}

// =====================================================================
extern "C" void kernel_launch(void* const* d_in, const int* in_sizes, int n_in,
                              void* d_out, int out_size, void* d_ws, size_t ws_size,
                              hipStream_t stream) {
  (void)in_sizes; (void)n_in; (void)out_size; (void)ws_size;
  float* out = (float*)d_out;
  float* ws = (float*)d_ws;

  MegaArgs a;
  a.x    = (const float*)d_in[0];
  a.c    = (const float*)d_in[1];
  a.fc1w = (const float*)d_in[2];  a.fc1b = (const float*)d_in[3];
  a.fc2w = (const float*)d_in[4];  a.fc2b = (const float*)d_in[5];
  a.muw  = (const float*)d_in[6];  a.mub  = (const float*)d_in[7];
  a.lvw  = (const float*)d_in[8];  a.lvb  = (const float*)d_in[9];
  a.g0w  = (const float*)d_in[10]; a.g0b  = (const float*)d_in[11];
  a.g1w  = (const float*)d_in[12]; a.g1b  = (const float*)d_in[13];
  a.g2w  = (const float*)d_in[14]; a.g2b  = (const float*)d_in[15];
  a.w0   = (const float*)d_in[16]; a.b0   = (const float*)d_in[17];
  a.w1   = (const float*)d_in[18]; a.b1   = (const float*)d_in[19];
  a.w2   = (const float*)d_in[20]; a.b2   = (const float*)d_in[21];

  a.outY  = out;
  a.outMu = out + 2048 * 267;
  a.outLv = a.outMu + 2048 * 32;

  a.Ax   = (unsigned short*)(ws);
  a.Axh  = (unsigned short*)(ws + 557056);
  a.Axh2 = (unsigned short*)(ws + 1114112);
  a.A0   = (unsigned short*)(ws + 1671168);
  a.A1   = (unsigned short*)(ws + 1998848);
  a.A2   = (unsigned short*)(ws + 2293760);
  a.fc1t = (unsigned short*)(ws + 2588672);
  a.fc2t = (unsigned short*)(ws + 2658304);
  a.mlvt = (unsigned short*)(ws + 2727936);
  a.g0t  = (unsigned short*)(ws + 2745344);
  a.g1t  = (unsigned short*)(ws + 2755584);
  a.w0b  = (unsigned short*)(ws + 2757632);
  a.w1b  = (unsigned short*)(ws + 3085312);
  a.w2b  = (unsigned short*)(ws + 3380224);
  a.cf   = ws + 3687808;

  dim3 blkP(256), blkG(128);
  k_prep<<<1673, blkP, 0, stream>>>(a);

  void* kp[] = { (void*)&a };
  hipError_t err = hipLaunchCooperativeKernel((const void*)mega_kernel,
                                              dim3(1024), dim3(128), kp, 0, stream);
  if (err != hipSuccess) {
    // fallback: R7-style separate dispatches
    pipe16<17, 1, 12, true, false><<<dim3(64, 16), blkG, 0, stream>>>(
        a.Ax, a.fc1t, 256, a.fc1b, nullptr, a.Axh, 544, 267, nullptr);
    pipe16<17, 1, 12, true, false><<<dim3(64, 16), blkG, 0, stream>>>(
        a.Axh, a.fc2t, 256, a.fc2b, nullptr, a.Axh2, 544, 267, nullptr);
    k_mulv_gate_fb<<<128, blkG, 0, stream>>>(a);
    pipe16<10, 8, 16, true, false><<<dim3(64, 16), blkG, 0, stream>>>(
        a.A0, a.w0b, 256, a.b0, a.cf, a.A1, 288, 32, nullptr);
    pipe16<9, 8, 16, true, false><<<dim3(64, 16), blkG, 0, stream>>>(
        a.A1, a.w1b, 256, a.b1, a.cf, a.A2, 288, 32, nullptr);
    pipe16<9, 8, 16, false, true><<<dim3(64, 17), blkG, 0, stream>>>(
        a.A2, a.w2b, 267, a.b2, a.cf, nullptr, 0, 0, a.outY);
  }
}

// Round 9
// 386.435 us; speedup vs baseline: 1.9480x; 1.9480x over previous
//
#include <hip/hip_runtime.h>
#include <math.h>
#include <stdint.h>

#define DI __device__ __forceinline__

typedef __attribute__((ext_vector_type(8))) short bf16x8;
typedef __attribute__((ext_vector_type(4))) float f32x4;
typedef __attribute__((ext_vector_type(4))) int i32x4;

DI float elu_f(float v) { return v > 0.f ? v : expm1f(v); }

DI unsigned short f2bf(float f) {  // fp32 -> bf16 RNE
  uint32_t u = __float_as_uint(f);
  return (unsigned short)((u + 0x7FFFu + ((u >> 16) & 1u)) >> 16);
}

// ---------------- threefry2x32 (JAX, 20 rounds)
DI void threefry2x32(uint32_t k0, uint32_t k1, uint32_t& x0, uint32_t& x1) {
  uint32_t ks0 = k0, ks1 = k1, ks2 = k0 ^ k1 ^ 0x1BD11BDAu;
  x0 += ks0; x1 += ks1;
#define TFR(r) { x0 += x1; x1 = (x1 << r) | (x1 >> (32 - r)); x1 ^= x0; }
  TFR(13) TFR(15) TFR(26) TFR(6)   x0 += ks1; x1 += ks2 + 1u;
  TFR(17) TFR(29) TFR(16) TFR(24)  x0 += ks2; x1 += ks0 + 2u;
  TFR(13) TFR(15) TFR(26) TFR(6)   x0 += ks0; x1 += ks1 + 3u;
  TFR(17) TFR(29) TFR(16) TFR(24)  x0 += ks1; x1 += ks2 + 4u;
  TFR(13) TFR(15) TFR(26) TFR(6)   x0 += ks2; x1 += ks0 + 5u;
#undef TFR
}

DI float erfinv_f(float x) {  // Giles erfinv (rel err ~1e-6 << bf16 quantum)
  float w = -logf((1.0f - x) * (1.0f + x));
  float p;
  if (w < 5.0f) {
    w -= 2.5f;
    p = 2.81022636e-08f;
    p = fmaf(p, w, 3.43273939e-07f);
    p = fmaf(p, w, -3.5233877e-06f);
    p = fmaf(p, w, -4.39150654e-06f);
    p = fmaf(p, w, 0.00021858087f);
    p = fmaf(p, w, -0.00125372503f);
    p = fmaf(p, w, -0.00417768164f);
    p = fmaf(p, w, 0.246640727f);
    p = fmaf(p, w, 1.50140941f);
  } else {
    w = sqrtf(w) - 3.0f;
    p = -0.000200214257f;
    p = fmaf(p, w, 0.000100950558f);
    p = fmaf(p, w, 0.00134934322f);
    p = fmaf(p, w, -0.00367342844f);
    p = fmaf(p, w, 0.00573950773f);
    p = fmaf(p, w, -0.0076224613f);
    p = fmaf(p, w, 0.00943887047f);
    p = fmaf(p, w, 1.00167406f);
    p = fmaf(p, w, 2.83297682f);
  }
  return p * x;
}

struct MegaArgs {
  const float *x, *c;
  const float *fc1w, *fc1b, *fc2w, *fc2b, *muw, *mub, *lvw, *lvb;
  const float *g0w, *g0b, *g1w, *g1b, *g2w, *g2b;
  const float *w0, *b0, *w1, *b1, *w2, *b2;
  unsigned short *fc1t, *fc2t, *mlvt, *g0t, *g1t, *w0b, *w1b, *w2b;
  float *outY, *outMu, *outLv;
};

// =====================================================================
// seg: one wave computes TPW 16x16 output tiles for 16 rows whose A-panel
// is LDS-resident. A-frags loaded once (reused across tiles/experts),
// W streamed global->register ring (D=8, AITER-style fine vmcnt).
// MODE: 0 bf16->LDS (+bias,elu) | 1 f32->LDS raw | 4 f32->LDS (+bias,elu)
//       2 NE-fold bf16->LDS (elu) | 3 NE-fold f32->global (no act)
template <int KT, int NE, int TPW, int MODE>
DI void seg(int lane,
            const unsigned short* AL, int ldA,
            const unsigned short* __restrict__ Wt, int N, int tbase,
            const float* __restrict__ biasG, const float* cfsL,
            unsigned short* outB, int ldOB, int coffB,
            float* outF, int ldOF) {
  constexpr int Kp = KT * 32, D = 8, TT = TPW * NE * KT;
  const int q = lane >> 4, l16 = lane & 15;
  bf16x8 areg[KT];
#pragma unroll
  for (int c = 0; c < KT; c++)
    areg[c] = *(const bf16x8*)(AL + l16 * ldA + c * 32 + q * 8);
  int gc[TPW];
  const unsigned short* wl[TPW];
  float br[TPW][NE];
  float cfr[(NE > 1) ? NE * 4 : 1];
#pragma unroll
  for (int t = 0; t < TPW; t++) {
    gc[t] = tbase + t * 16 + l16;
    int wr = (gc[t] < N) ? gc[t] : N - 1;
    wl[t] = Wt + (size_t)wr * Kp + q * 8;
    if (MODE != 1) {
#pragma unroll
      for (int e = 0; e < NE; e++)
        br[t][e] = (gc[t] < N) ? biasG[(size_t)e * N + gc[t]] : 0.f;
    }
  }
  if (NE > 1) {
#pragma unroll
    for (int e = 0; e < NE; e++)
#pragma unroll
      for (int r = 0; r < 4; r++)
        cfr[e * 4 + r] = cfsL[(q * 4 + r) * 8 + e];
  }
  bf16x8 ring[D];
#pragma unroll
  for (int g = 0; g < D; g++) {
    if (g < TT) {
      int t = g / (NE * KT), e = (g / KT) % NE, c = g % KT;
      ring[g] = *(const bf16x8*)(wl[t] + (size_t)e * N * Kp + c * 32);
    }
  }
  f32x4 acc[TPW], accF[TPW];
#pragma unroll
  for (int t = 0; t < TPW; t++) {
    acc[t] = {0.f, 0.f, 0.f, 0.f};
    accF[t] = {0.f, 0.f, 0.f, 0.f};
  }
#pragma unroll
  for (int g = 0; g < TT; g++) {
    const int t = g / (NE * KT), e = (g / KT) % NE, c = g % KT;
    acc[t] = __builtin_amdgcn_mfma_f32_16x16x32_bf16(areg[c], ring[g % D], acc[t], 0, 0, 0);
    if (g + D < TT) {
      int t2 = (g + D) / (NE * KT), e2 = ((g + D) / KT) % NE, c2 = (g + D) % KT;
      ring[g % D] = *(const bf16x8*)(wl[t2] + (size_t)e2 * N * Kp + c2 * 32);
    }
    if (NE > 1 && c == KT - 1) {  // expert boundary: exact fp32 fold
#pragma unroll
      for (int r = 0; r < 4; r++) {
        accF[t][r] += cfr[e * 4 + r] * (acc[t][r] + br[t][e]);
        acc[t][r] = 0.f;
      }
    }
  }
#pragma unroll
  for (int t = 0; t < TPW; t++) {
    if (gc[t] >= N) continue;
#pragma unroll
    for (int r = 0; r < 4; r++) {
      const int row = q * 4 + r;
      if (MODE == 0)
        outB[row * ldOB + coffB + gc[t]] = f2bf(elu_f(acc[t][r] + br[t][0]));
      else if (MODE == 1)
        outF[row * ldOF + gc[t]] = acc[t][r];
      else if (MODE == 4)
        outF[row * ldOF + gc[t]] = elu_f(acc[t][r] + br[t][0]);
      else if (MODE == 2)
        outB[row * ldOB + coffB + gc[t]] = f2bf(elu_f(accF[t][r]));
      else
        outF[(size_t)row * ldOF + gc[t]] = accF[t][r];
    }
  }
}

// =====================================================================
// row_net: each block = 16 rows, ENTIRE network, activations LDS-only.
// 512 thr = 8 waves (2/SIMD); phases partition columns across waves.
__global__ __launch_bounds__(512, 2) void row_net(MegaArgs a) {
  __shared__ __align__(16) unsigned char SM[46336];
  // regions:
  unsigned short* Acat0 = (unsigned short*)SM;             // [16][552] x|c -> x|h2
  unsigned short* Acat1 = (unsigned short*)(SM + 17664);   // [16][552] x|h1
  unsigned short* A0p   = (unsigned short*)(SM + 35328);   // [16][328] z|c
  float* cfs = (float*)(SM + 45824);                       // [16][8]
  // overlays on Acat0 (dead after mulv):
  unsigned short* A1p = Acat0;                             // [16][296] z|h(moe0)
  float* gB   = (float*)(SM + 9472);                       // [16][65]
  float* lg   = (float*)(SM + 13632);                      // [16][8]
  float* g2wT = (float*)(SM + 14144);                      // [64][8]
  // overlays on Acat1 (dead after fc2):
  unsigned short* A2p = Acat1;                             // [16][296] z|h(moe1)
  float* mlvS = (float*)(SM + 17664 + 9472);               // [16][65]
  unsigned short* gaB = (unsigned short*)(SM + 17664 + 13632);  // [16][72]

  const int tid = threadIdx.x, lane = tid & 63, wv = tid >> 6;
  const int m0 = blockIdx.x * 16;

  // ---- phase 1: stage x|c (+pads) ----
  for (int idx = tid; idx < 16 * 267; idx += 512) {
    int r = idx / 267, k = idx % 267;
    unsigned short xv = f2bf(a.x[(size_t)(m0 + r) * 267 + k]);
    Acat0[r * 552 + k] = xv;
    Acat1[r * 552 + k] = xv;
    unsigned short cv = f2bf(a.c[(size_t)(m0 + r) * 267 + k]);
    Acat0[r * 552 + 267 + k] = cv;
    A0p[r * 328 + 32 + k] = cv;
  }
  for (int idx = tid; idx < 16 * 18; idx += 512) {  // Acat0 534..551
    int r = idx / 18, k = idx % 18;
    Acat0[r * 552 + 534 + k] = 0;
  }
  for (int idx = tid; idx < 16 * 29; idx += 512) {  // Acat1 523..551
    int r = idx / 29, k = idx % 29;
    Acat1[r * 552 + 523 + k] = 0;
  }
  for (int idx = tid; idx < 16 * 29; idx += 512) {  // A0p 299..327
    int r = idx / 29, k = idx % 29;
    A0p[r * 328 + 299 + k] = 0;
  }
  __syncthreads();

  // ---- fc1: h1 = elu([x|c] @ fc1t^T + b) -> Acat1[.,267..522] ----
  seg<17, 1, 2, 0>(lane, Acat0, 552, a.fc1t, 256, wv * 32, a.fc1b, nullptr,
                   Acat1, 552, 267, nullptr, 0);
  __syncthreads();
  // ---- fc2 -> Acat0[.,267..522]; zero Acat0 pad 523..543 ----
  seg<17, 1, 2, 0>(lane, Acat1, 552, a.fc2t, 256, wv * 32, a.fc2b, nullptr,
                   Acat0, 552, 267, nullptr, 0);
  for (int idx = tid; idx < 16 * 21; idx += 512) {
    int r = idx / 21, k = idx % 21;
    Acat0[r * 552 + 523 + k] = 0;
  }
  __syncthreads();
  // ---- mu/lv (waves 0..3, 64 out cols) -> mlvS raw ----
  if (wv < 4)
    seg<17, 1, 1, 1>(lane, Acat0, 552, a.mlvt, 64, wv * 16, nullptr, nullptr,
                     nullptr, 0, 0, mlvS, 65);
  __syncthreads();
  // ---- z = mu + eps*exp(0.5*lv), exact JAX threefry-normal ----
  if (tid < 128) {
    const int m = tid >> 3, j0 = (tid & 7) * 4, R = m0 + m;
#pragma unroll
    for (int jj = 0; jj < 4; jj++) {
      int j = j0 + jj;
      float mu = mlvS[m * 65 + j] + a.mub[j];
      float lvv = mlvS[m * 65 + j + 32] + a.lvb[j];
      uint32_t x0 = 0u, x1 = (uint32_t)(R * 32 + j);
      threefry2x32(0u, 42u, x0, x1);
      uint32_t bits = x0 ^ x1;
      float f = __uint_as_float((bits >> 9) | 0x3F800000u) - 1.0f;
      const float lo = -0.99999994039535522461f;
      float u = fmaf(f, 2.0f, lo);
      u = fmaxf(u, lo);
      float eps = 1.41421356237f * erfinv_f(u);
      float z = fmaf(eps, expf(0.5f * lvv), mu);
      a.outMu[(size_t)R * 32 + j] = mu;
      a.outLv[(size_t)R * 32 + j] = lvv;
      unsigned short zb = f2bf(z);
      A0p[m * 328 + j] = zb;
      A1p[m * 296 + j] = zb;
      A2p[m * 296 + j] = zb;
    }
  }
  __syncthreads();
  // ---- g0 (waves 0..3) -> gaB bf16; waves 4..7 stage g2wT ----
  if (wv < 4)
    seg<10, 1, 1, 0>(lane, A0p, 328, a.g0t, 64, wv * 16, a.g0b, nullptr,
                     gaB, 72, 0, nullptr, 0);
  if (tid >= 256) {
    for (int idx = tid - 256; idx < 512; idx += 256)
      g2wT[(idx & 63) * 8 + (idx >> 6)] = a.g2w[idx];
  }
  __syncthreads();
  // ---- g1 (waves 0..3) -> gB f32 ----
  if (wv < 4)
    seg<2, 1, 1, 4>(lane, gaB, 72, a.g1t, 64, wv * 16, a.g1b, nullptr,
                    nullptr, 0, 0, gB, 65);
  __syncthreads();
  // ---- g2 logits ----
  if (tid < 128) {
    int r = tid >> 3, e = tid & 7;
    float d = a.g2b[e];
#pragma unroll 8
    for (int k = 0; k < 64; k++) d = fmaf(gB[r * 65 + k], g2wT[k * 8 + e], d);
    lg[r * 8 + e] = d;
  }
  __syncthreads();
  // ---- softmax -> cfs ----
  if (tid < 16) {
    float mx = lg[tid * 8];
#pragma unroll
    for (int e2 = 1; e2 < 8; e2++) mx = fmaxf(mx, lg[tid * 8 + e2]);
    float s = 0.f, ex[8];
#pragma unroll
    for (int e2 = 0; e2 < 8; e2++) { ex[e2] = expf(lg[tid * 8 + e2] - mx); s += ex[e2]; }
    float inv = 1.f / s;
#pragma unroll
    for (int e2 = 0; e2 < 8; e2++) cfs[tid * 8 + e2] = ex[e2] * inv;
  }
  __syncthreads();
  // ---- moe0: A0p(z|c) -> A1p[.,32..287] ----
  seg<10, 8, 2, 2>(lane, A0p, 328, a.w0b, 256, wv * 32, a.b0, cfs,
                   A1p, 296, 32, nullptr, 0);
  __syncthreads();
  // ---- moe1: A1p(z|h) -> A2p[.,32..287] ----
  seg<9, 8, 2, 2>(lane, A1p, 296, a.w1b, 256, wv * 32, a.b1, cfs,
                  A2p, 296, 32, nullptr, 0);
  __syncthreads();
  // ---- moe2: A2p(z|h) -> outY (f32, no act) ----
  float* oY = a.outY + (size_t)m0 * 267;
  seg<9, 8, 2, 3>(lane, A2p, 296, a.w2b, 267, wv * 32, a.b2, cfs,
                  nullptr, 0, 0, oY, 267);
  if (wv == 0)
    seg<9, 8, 1, 3>(lane, A2p, 296, a.w2b, 267, 256, a.b2, cfs,
                    nullptr, 0, 0, oY, 267);
}

// =====================================================================
// prep: weights only (convert + expert tile-transpose), 1161 blocks
__global__ __launch_bounds__(256) void k_prep(MegaArgs a) {
  __shared__ __align__(16) unsigned short T[64][72];
  const int bb = blockIdx.x, tid = threadIdx.x;
  if (bb < 640) {
    int r = bb;
    const float* src; unsigned short* dst; int Ks, Kp2;
    if (r < 256)      { src = a.fc1w + (size_t)r * 534; dst = a.fc1t + (size_t)r * 544; Ks = 534; Kp2 = 544; }
    else if (r < 512) { int n = r - 256; src = a.fc2w + (size_t)n * 523; dst = a.fc2t + (size_t)n * 544; Ks = 523; Kp2 = 544; }
    else if (r < 576) { int n = r - 512; src = (n < 32) ? (a.muw + (size_t)n * 523) : (a.lvw + (size_t)(n - 32) * 523);
                        dst = a.mlvt + (size_t)n * 544; Ks = 523; Kp2 = 544; }
    else              { int n = r - 576; src = a.g0w + (size_t)n * 299; dst = a.g0t + (size_t)n * 320; Ks = 299; Kp2 = 320; }
    for (int k = tid; k < Kp2; k += 256) dst[k] = (k < Ks) ? f2bf(src[k]) : (unsigned short)0;
  } else if (bb == 640) {
    for (int k = tid; k < 4096; k += 256) a.g1t[k] = f2bf(a.g1w[k]);
  } else {
    int t = bb - 641;
    const float* W; unsigned short* D; int K, N2, Kp2, ldW, e, kt, nt;
    if (t < 160)      { e = t / 20;  int lt = t % 20;  kt = lt / 4; nt = lt % 4; W = a.w0; D = a.w0b; K = 299; N2 = 256; Kp2 = 320; ldW = 256; }
    else if (t < 320) { int u = t - 160; e = u / 20; int lt = u % 20; kt = lt / 4; nt = lt % 4; W = a.w1; D = a.w1b; K = 288; N2 = 256; Kp2 = 288; ldW = 256; }
    else              { int u = t - 320; e = u / 25; int lt = u % 25; kt = lt / 5; nt = lt % 5; W = a.w2; D = a.w2b; K = 288; N2 = 267; Kp2 = 288; ldW = 267; }
    const int k0 = kt * 64, n0 = nt * 64;
    const float* We = W + (size_t)e * K * ldW;
    const int jj = tid & 63, ii0 = tid >> 6;
#pragma unroll
    for (int p = 0; p < 16; p++) {
      int i = ii0 + p * 4;
      int gk = k0 + i, gn = n0 + jj;
      float v = (gk < K && gn < N2) ? We[(size_t)gk * ldW + gn] : 0.f;
      T[jj][i] = f2bf(v);
    }
    __syncthreads();
    int j = tid >> 2, chb = tid & 3;
    int gn = n0 + j;
    if (gn < N2) {
      unsigned short* drow = D + ((size_t)e * N2 + gn) * Kp2 + k0;
#pragma unroll
      for (int s = 0; s < 2; s++) {
        int ch = chb + s * 4;
        if (k0 + ch * 8 < Kp2) {
          i32x4 v = *(i32x4*)(&T[j][ch * 8]);
          *(i32x4*)(drow + ch * 8) = v;
        }
      }
    }
  }
}

// =====================================================================
extern "C" void kernel_launch(void* const* d_in, const int* in_sizes, int n_in,
                              void* d_out, int out_size, void* d_ws, size_t ws_size,
                              hipStream_t stream) {
  (void)in_sizes; (void)n_in; (void)out_size; (void)ws_size;
  float* out = (float*)d_out;
  float* ws = (float*)d_ws;

  MegaArgs a;
  a.x    = (const float*)d_in[0];
  a.c    = (const float*)d_in[1];
  a.fc1w = (const float*)d_in[2];  a.fc1b = (const float*)d_in[3];
  a.fc2w = (const float*)d_in[4];  a.fc2b = (const float*)d_in[5];
  a.muw  = (const float*)d_in[6];  a.mub  = (const float*)d_in[7];
  a.lvw  = (const float*)d_in[8];  a.lvb  = (const float*)d_in[9];
  a.g0w  = (const float*)d_in[10]; a.g0b  = (const float*)d_in[11];
  a.g1w  = (const float*)d_in[12]; a.g1b  = (const float*)d_in[13];
  a.g2w  = (const float*)d_in[14]; a.g2b  = (const float*)d_in[15];
  a.w0   = (const float*)d_in[16]; a.b0   = (const float*)d_in[17];
  a.w1   = (const float*)d_in[18]; a.b1   = (const float*)d_in[19];
  a.w2   = (const float*)d_in[20]; a.b2   = (const float*)d_in[21];

  a.outY  = out;
  a.outMu = out + 2048 * 267;
  a.outLv = a.outMu + 2048 * 32;

  a.fc1t = (unsigned short*)(ws);            // 256x544
  a.fc2t = (unsigned short*)(ws + 69632);    // 256x544
  a.mlvt = (unsigned short*)(ws + 139264);   // 64x544
  a.g0t  = (unsigned short*)(ws + 156672);   // 64x320
  a.g1t  = (unsigned short*)(ws + 166912);   // 64x64
  a.w0b  = (unsigned short*)(ws + 168960);   // 8x256x320
  a.w1b  = (unsigned short*)(ws + 496640);   // 8x256x288
  a.w2b  = (unsigned short*)(ws + 791552);   // 8x267x288

  k_prep<<<1161, dim3(256), 0, stream>>>(a);
  row_net<<<128, dim3(512), 0, stream>>>(a);
}

// Round 10
// 175.632 us; speedup vs baseline: 4.2862x; 2.2003x over previous
//
#include <hip/hip_runtime.h>
#include <math.h>
#include <stdint.h>

#define DI __device__ __forceinline__

typedef __attribute__((ext_vector_type(8))) short bf16x8;
typedef __attribute__((ext_vector_type(4))) float f32x4;
typedef __attribute__((ext_vector_type(4))) int i32x4;

DI float elu_f(float v) { return v > 0.f ? v : expm1f(v); }

DI unsigned short f2bf(float f) {  // fp32 -> bf16 RNE
  uint32_t u = __float_as_uint(f);
  return (unsigned short)((u + 0x7FFFu + ((u >> 16) & 1u)) >> 16);
}

// ---------------- threefry2x32 (JAX, 20 rounds)
DI void threefry2x32(uint32_t k0, uint32_t k1, uint32_t& x0, uint32_t& x1) {
  uint32_t ks0 = k0, ks1 = k1, ks2 = k0 ^ k1 ^ 0x1BD11BDAu;
  x0 += ks0; x1 += ks1;
#define TFR(r) { x0 += x1; x1 = (x1 << r) | (x1 >> (32 - r)); x1 ^= x0; }
  TFR(13) TFR(15) TFR(26) TFR(6)   x0 += ks1; x1 += ks2 + 1u;
  TFR(17) TFR(29) TFR(16) TFR(24)  x0 += ks2; x1 += ks0 + 2u;
  TFR(13) TFR(15) TFR(26) TFR(6)   x0 += ks0; x1 += ks1 + 3u;
  TFR(17) TFR(29) TFR(16) TFR(24)  x0 += ks1; x1 += ks2 + 4u;
  TFR(13) TFR(15) TFR(26) TFR(6)   x0 += ks2; x1 += ks0 + 5u;
#undef TFR
}

DI float erfinv_f(float x) {  // Giles erfinv (rel err ~1e-6 << bf16 quantum)
  float w = -logf((1.0f - x) * (1.0f + x));
  float p;
  if (w < 5.0f) {
    w -= 2.5f;
    p = 2.81022636e-08f;
    p = fmaf(p, w, 3.43273939e-07f);
    p = fmaf(p, w, -3.5233877e-06f);
    p = fmaf(p, w, -4.39150654e-06f);
    p = fmaf(p, w, 0.00021858087f);
    p = fmaf(p, w, -0.00125372503f);
    p = fmaf(p, w, -0.00417768164f);
    p = fmaf(p, w, 0.246640727f);
    p = fmaf(p, w, 1.50140941f);
  } else {
    w = sqrtf(w) - 3.0f;
    p = -0.000200214257f;
    p = fmaf(p, w, 0.000100950558f);
    p = fmaf(p, w, 0.00134934322f);
    p = fmaf(p, w, -0.00367342844f);
    p = fmaf(p, w, 0.00573950773f);
    p = fmaf(p, w, -0.0076224613f);
    p = fmaf(p, w, 0.00943887047f);
    p = fmaf(p, w, 1.00167406f);
    p = fmaf(p, w, 2.83297682f);
  }
  return p * x;
}

struct MegaArgs {
  const float *x, *c;
  const float *fc1w, *fc1b, *fc2w, *fc2b, *muw, *mub, *lvw, *lvb;
  const float *g0w, *g0b, *g1w, *g1b, *g2w, *g2b;
  const float *w0, *b0, *w1, *b1, *w2, *b2;
  unsigned short *Ax, *Axh, *Axh2, *A0, *A1, *A2;
  unsigned short *fc1t, *fc2t, *mlvt, *g0t, *g1t, *w0b, *w1b, *w2b;
  float *cf, *outY, *outMu, *outLv;
};

// =====================================================================
// pipe32: block = 32 rows x 32 cols, 128 thr = 2 waves SPLITTING COLUMNS.
// Each wave: TWO 16-row MFMA tiles x its private 16-col W slice -> W is
// read once per 32 rows (half of R7's traffic), 2 independent MFMAs per
// ring slot (ILP replaces the halved TLP). A-frags direct global->VGPR,
// W via register ring (D-deep, fine-grained vmcnt). LDS: bias/coeff only.
template <int KT, int NE, int D, bool ELU, bool OUTF32>
__global__ __launch_bounds__(128, 2)
void pipe32(const unsigned short* __restrict__ A,          // [2048][Kp]
            const unsigned short* __restrict__ Wt, int N,  // [NE][N][Kp]
            const float* __restrict__ bias,                // [NE][N]
            const float* __restrict__ cfp,                 // [2048][8] | null
            unsigned short* __restrict__ Cb, int ldcb, int cb_off,
            float* __restrict__ Cf) {
  constexpr int Kp = KT * 32, TT = NE * KT;
  __shared__ float bias_s[NE * 32];
  __shared__ float cfs[(NE > 1) ? 256 : 1];
  const int tid = threadIdx.x, lane = tid & 63, wv = tid >> 6;  // wv 0,1
  const int q = lane >> 4, l16 = lane & 15;
  const int m0 = blockIdx.x * 32;
  const int n0 = blockIdx.y * 32 + wv * 16;   // wave-private col slice
  const int gc = n0 + l16;
  const int wrow = (gc < N) ? gc : (N - 1);   // clamp: OOB lanes load junk, never stored
  const unsigned short* wlane = Wt + (size_t)wrow * Kp + q * 8;

  bf16x8 ring[D];
#pragma unroll
  for (int g = 0; g < D; g++) {
    if (g < TT) {
      int e = g / KT, c = g % KT;
      ring[g] = *(const bf16x8*)(wlane + (size_t)e * N * Kp + c * 32);
    }
  }
  bf16x8 areg[2][KT];
#pragma unroll
  for (int t = 0; t < 2; t++) {
    const unsigned short* alane = A + (size_t)(m0 + t * 16 + l16) * Kp + q * 8;
#pragma unroll
    for (int c = 0; c < KT; c++) areg[t][c] = *(const bf16x8*)(alane + c * 32);
  }

  if (NE == 1) {
    if (tid < 32) {
      int col = blockIdx.y * 32 + tid;
      bias_s[tid] = (col < N) ? bias[col] : 0.f;
    }
  } else {
    for (int idx = tid; idx < NE * 32; idx += 128) {
      int e = idx >> 5, col = blockIdx.y * 32 + (idx & 31);
      bias_s[idx] = (col < N) ? bias[(size_t)e * N + col] : 0.f;
    }
    for (int idx = tid; idx < 256; idx += 128)
      cfs[idx] = cfp[(size_t)(m0 + (idx >> 3)) * 8 + (idx & 7)];
  }
  __syncthreads();

  f32x4 acc[2] = {{0.f, 0.f, 0.f, 0.f}, {0.f, 0.f, 0.f, 0.f}};
  f32x4 accF[2] = {{0.f, 0.f, 0.f, 0.f}, {0.f, 0.f, 0.f, 0.f}};
#pragma unroll
  for (int g = 0; g < TT; g++) {
    const int e = g / KT, c = g % KT;
    bf16x8 bv = ring[g % D];
    acc[0] = __builtin_amdgcn_mfma_f32_16x16x32_bf16(areg[0][c], bv, acc[0], 0, 0, 0);
    acc[1] = __builtin_amdgcn_mfma_f32_16x16x32_bf16(areg[1][c], bv, acc[1], 0, 0, 0);
    if (g + D < TT) {
      int e2 = (g + D) / KT, c2 = (g + D) % KT;
      ring[g % D] = *(const bf16x8*)(wlane + (size_t)e2 * N * Kp + c2 * 32);
    }
    if (NE > 1 && c == KT - 1) {  // expert boundary: exact fp32 fold
      float bv2 = bias_s[e * 32 + wv * 16 + l16];
#pragma unroll
      for (int t = 0; t < 2; t++)
#pragma unroll
        for (int r = 0; r < 4; r++) {
          float ce = cfs[(t * 16 + q * 4 + r) * 8 + e];
          accF[t][r] += ce * (acc[t][r] + bv2);
          acc[t][r] = 0.f;
        }
    }
  }

  if (gc < N) {
#pragma unroll
    for (int t = 0; t < 2; t++)
#pragma unroll
      for (int r = 0; r < 4; r++) {
        int row = m0 + t * 16 + q * 4 + r;
        float v = (NE > 1) ? accF[t][r] : (acc[t][r] + bias_s[wv * 16 + l16]);
        if (ELU) v = elu_f(v);
        if (OUTF32) Cf[(size_t)row * 267 + gc] = v;
        else Cb[(size_t)row * ldcb + cb_off + gc] = f2bf(v);
      }
  }
}

// =====================================================================
// prep (one dispatch, 1673 blocks x 256 thr) — verbatim R5-R7
__global__ __launch_bounds__(256) void k_prep(MegaArgs a) {
  __shared__ __align__(16) unsigned short T[64][72];
  const int bb = blockIdx.x, tid = threadIdx.x;
  if (bb < 512) {
    for (int rr = 0; rr < 4; rr++) {
      int b = bb * 4 + rr;
      const float* xr = a.x + (size_t)b * 267;
      const float* cr = a.c + (size_t)b * 267;
      unsigned short* axr = a.Ax + (size_t)b * 544;
      for (int k = tid; k < 544; k += 256) {
        float v = (k < 267) ? xr[k] : ((k < 534) ? cr[k - 267] : 0.f);
        axr[k] = f2bf(v);
      }
      unsigned short* ahr = a.Axh + (size_t)b * 544;
      unsigned short* ah2 = a.Axh2 + (size_t)b * 544;
      for (int k = tid; k < 267; k += 256) { unsigned short v = f2bf(xr[k]); ahr[k] = v; ah2[k] = v; }
      for (int k = 523 + tid; k < 544; k += 256) { ahr[k] = 0; ah2[k] = 0; }
      unsigned short* a0r = a.A0 + (size_t)b * 320;
      for (int k = tid; k < 288; k += 256)
        a0r[32 + k] = (k < 267) ? f2bf(cr[k]) : (unsigned short)0;
    }
  } else if (bb < 1152) {
    int r = bb - 512;
    const float* src; unsigned short* dst; int Ks, Kp2;
    if (r < 256)      { src = a.fc1w + (size_t)r * 534; dst = a.fc1t + (size_t)r * 544; Ks = 534; Kp2 = 544; }
    else if (r < 512) { int n = r - 256; src = a.fc2w + (size_t)n * 523; dst = a.fc2t + (size_t)n * 544; Ks = 523; Kp2 = 544; }
    else if (r < 576) { int n = r - 512; src = (n < 32) ? (a.muw + (size_t)n * 523) : (a.lvw + (size_t)(n - 32) * 523);
                        dst = a.mlvt + (size_t)n * 544; Ks = 523; Kp2 = 544; }
    else              { int n = r - 576; src = a.g0w + (size_t)n * 299; dst = a.g0t + (size_t)n * 320; Ks = 299; Kp2 = 320; }
    for (int k = tid; k < Kp2; k += 256) dst[k] = (k < Ks) ? f2bf(src[k]) : (unsigned short)0;
  } else if (bb == 1152) {
    for (int k = tid; k < 4096; k += 256) a.g1t[k] = f2bf(a.g1w[k]);
  } else {
    int t = bb - 1153;
    const float* W; unsigned short* D; int K, N2, Kp2, ldW, e, kt, nt;
    if (t < 160)      { e = t / 20;  int lt = t % 20;  kt = lt / 4; nt = lt % 4; W = a.w0; D = a.w0b; K = 299; N2 = 256; Kp2 = 320; ldW = 256; }
    else if (t < 320) { int u = t - 160; e = u / 20; int lt = u % 20; kt = lt / 4; nt = lt % 4; W = a.w1; D = a.w1b; K = 288; N2 = 256; Kp2 = 288; ldW = 256; }
    else              { int u = t - 320; e = u / 25; int lt = u % 25; kt = lt / 5; nt = lt % 5; W = a.w2; D = a.w2b; K = 288; N2 = 267; Kp2 = 288; ldW = 267; }
    const int k0 = kt * 64, n0 = nt * 64;
    const float* We = W + (size_t)e * K * ldW;
    const int jj = tid & 63, ii0 = tid >> 6;
#pragma unroll
    for (int p = 0; p < 16; p++) {
      int i = ii0 + p * 4;
      int gk = k0 + i, gn = n0 + jj;
      float v = (gk < K && gn < N2) ? We[(size_t)gk * ldW + gn] : 0.f;
      T[jj][i] = f2bf(v);
    }
    __syncthreads();
    int j = tid >> 2, chb = tid & 3;
    int gn = n0 + j;
    if (gn < N2) {
      unsigned short* drow = D + ((size_t)e * N2 + gn) * Kp2 + k0;
#pragma unroll
      for (int s = 0; s < 2; s++) {
        int ch = chb + s * 4;
        if (k0 + ch * 8 < Kp2) {
          i32x4 v = *(i32x4*)(&T[j][ch * 8]);
          *(i32x4*)(drow + ch * 8) = v;
        }
      }
    }
  }
}

// =====================================================================
// mu/lv GEMM + z + full gate stack — verbatim R7 (256 thr, 128 blocks)
__global__ __launch_bounds__(256, 2) void k_mulv_gate(MegaArgs a) {
  __shared__ float mlvS[16 * 65];
  __shared__ __align__(16) unsigned short A0p[16 * 328];
  __shared__ __align__(16) unsigned short gaB[16 * 72];
  __shared__ __align__(16) unsigned short g1B[64 * 72];
  __shared__ float g2wT[64 * 8];
  __shared__ float gB[16 * 65];
  __shared__ float lg[16 * 8];
  const int tid = threadIdx.x, lane = tid & 63, wid = tid >> 6;
  const int q = lane >> 4, l16 = lane & 15;
  const int m0 = blockIdx.x * 16;
  const int cl = wid * 16 + l16;  // 0..63

  const unsigned short* alane = a.Axh2 + (size_t)(m0 + l16) * 544 + q * 8;
  const unsigned short* wlA = a.mlvt + (size_t)cl * 544 + q * 8;
  bf16x8 ring[8];
#pragma unroll
  for (int g = 0; g < 8; g++) ring[g] = *(const bf16x8*)(wlA + g * 32);
  bf16x8 areg[17];
#pragma unroll
  for (int c = 0; c < 17; c++) areg[c] = *(const bf16x8*)(alane + c * 32);
  f32x4 acc = {0.f, 0.f, 0.f, 0.f};
#pragma unroll
  for (int g = 0; g < 17; g++) {
    acc = __builtin_amdgcn_mfma_f32_16x16x32_bf16(areg[g], ring[g % 8], acc, 0, 0, 0);
    if (g + 8 < 17) ring[g % 8] = *(const bf16x8*)(wlA + (g + 8) * 32);
  }
#pragma unroll
  for (int r = 0; r < 4; r++) mlvS[(q * 4 + r) * 65 + cl] = acc[r];
  for (int idx = tid; idx < 576; idx += 256) {
    int row = idx / 36, ch = 4 + idx % 36;
    *(i32x4*)(A0p + row * 328 + ch * 8) =
        *(const i32x4*)(a.A0 + (size_t)(m0 + row) * 320 + ch * 8);
  }
  if (tid < 16) { i32x4 z4 = {0, 0, 0, 0}; *(i32x4*)(A0p + tid * 328 + 320) = z4; }
  for (int idx = tid; idx < 512; idx += 256) {
    int row = idx >> 3, ch = idx & 7;
    *(i32x4*)(g1B + row * 72 + ch * 8) = *(const i32x4*)(a.g1t + (size_t)row * 64 + ch * 8);
  }
  for (int idx = tid; idx < 512; idx += 256)
    g2wT[(idx & 63) * 8 + (idx >> 6)] = a.g2w[idx];
  __syncthreads();

  {
    const int m = tid >> 4, j0 = (tid & 15) * 2, R = m0 + m;
#pragma unroll
    for (int jj = 0; jj < 2; jj++) {
      int j = j0 + jj;
      float mu = mlvS[m * 65 + j] + a.mub[j];
      float lvv = mlvS[m * 65 + j + 32] + a.lvb[j];
      uint32_t x0 = 0u, x1 = (uint32_t)(R * 32 + j);
      threefry2x32(0u, 42u, x0, x1);
      uint32_t bits = x0 ^ x1;
      float f = __uint_as_float((bits >> 9) | 0x3F800000u) - 1.0f;
      const float lo = -0.99999994039535522461f;
      float u = fmaf(f, 2.0f, lo);
      u = fmaxf(u, lo);
      float eps = 1.41421356237f * erfinv_f(u);
      float z = fmaf(eps, expf(0.5f * lvv), mu);
      a.outMu[(size_t)R * 32 + j] = mu;
      a.outLv[(size_t)R * 32 + j] = lvv;
      unsigned short zb = f2bf(z);
      A0p[m * 328 + j] = zb;
      a.A0[(size_t)R * 320 + j] = zb;
      a.A1[(size_t)R * 288 + j] = zb;
      a.A2[(size_t)R * 288 + j] = zb;
    }
  }
  __syncthreads();

  const unsigned short* wlC = a.g0t + (size_t)cl * 320 + q * 8;
  bf16x8 ring2[8];
#pragma unroll
  for (int g = 0; g < 8; g++) ring2[g] = *(const bf16x8*)(wlC + g * 32);
  f32x4 accC = {0.f, 0.f, 0.f, 0.f};
#pragma unroll
  for (int g = 0; g < 10; g++) {
    bf16x8 av = *(const bf16x8*)(A0p + l16 * 328 + g * 32 + q * 8);
    accC = __builtin_amdgcn_mfma_f32_16x16x32_bf16(av, ring2[g % 8], accC, 0, 0, 0);
    if (g + 8 < 10) ring2[g % 8] = *(const bf16x8*)(wlC + (g + 8) * 32);
  }
  {
    float bc = a.g0b[cl];
#pragma unroll
    for (int r = 0; r < 4; r++)
      gaB[(q * 4 + r) * 72 + cl] = f2bf(elu_f(accC[r] + bc));
  }
  __syncthreads();

  f32x4 accD = {0.f, 0.f, 0.f, 0.f};
#pragma unroll
  for (int tau = 0; tau < 2; tau++) {
    bf16x8 av = *(const bf16x8*)(gaB + l16 * 72 + tau * 32 + q * 8);
    bf16x8 bv = *(const bf16x8*)(g1B + cl * 72 + tau * 32 + q * 8);
    accD = __builtin_amdgcn_mfma_f32_16x16x32_bf16(av, bv, accD, 0, 0, 0);
  }
  {
    float bc = a.g1b[cl];
#pragma unroll
    for (int r = 0; r < 4; r++)
      gB[(q * 4 + r) * 65 + cl] = elu_f(accD[r] + bc);
  }
  __syncthreads();

  if (tid < 128) {
    int r = tid >> 3, e = tid & 7;
    float d = a.g2b[e];
#pragma unroll 8
    for (int k = 0; k < 64; k++) d = fmaf(gB[r * 65 + k], g2wT[k * 8 + e], d);
    lg[r * 8 + e] = d;
  }
  __syncthreads();
  if (tid < 16) {
    float mx = lg[tid * 8];
#pragma unroll
    for (int e2 = 1; e2 < 8; e2++) mx = fmaxf(mx, lg[tid * 8 + e2]);
    float s = 0.f, ex[8];
#pragma unroll
    for (int e2 = 0; e2 < 8; e2++) { ex[e2] = expf(lg[tid * 8 + e2] - mx); s += ex[e2]; }
    float inv = 1.f / s;
#pragma unroll
    for (int e2 = 0; e2 < 8; e2++) a.cf[(size_t)(m0 + tid) * 8 + e2] = ex[e2] * inv;
  }
}

// =====================================================================
extern "C" void kernel_launch(void* const* d_in, const int* in_sizes, int n_in,
                              void* d_out, int out_size, void* d_ws, size_t ws_size,
                              hipStream_t stream) {
  (void)in_sizes; (void)n_in; (void)out_size; (void)ws_size;
  float* out = (float*)d_out;
  float* ws = (float*)d_ws;

  MegaArgs a;
  a.x    = (const float*)d_in[0];
  a.c    = (const float*)d_in[1];
  a.fc1w = (const float*)d_in[2];  a.fc1b = (const float*)d_in[3];
  a.fc2w = (const float*)d_in[4];  a.fc2b = (const float*)d_in[5];
  a.muw  = (const float*)d_in[6];  a.mub  = (const float*)d_in[7];
  a.lvw  = (const float*)d_in[8];  a.lvb  = (const float*)d_in[9];
  a.g0w  = (const float*)d_in[10]; a.g0b  = (const float*)d_in[11];
  a.g1w  = (const float*)d_in[12]; a.g1b  = (const float*)d_in[13];
  a.g2w  = (const float*)d_in[14]; a.g2b  = (const float*)d_in[15];
  a.w0   = (const float*)d_in[16]; a.b0   = (const float*)d_in[17];
  a.w1   = (const float*)d_in[18]; a.b1   = (const float*)d_in[19];
  a.w2   = (const float*)d_in[20]; a.b2   = (const float*)d_in[21];

  a.outY  = out;
  a.outMu = out + 2048 * 267;
  a.outLv = a.outMu + 2048 * 32;

  a.Ax   = (unsigned short*)(ws);
  a.Axh  = (unsigned short*)(ws + 557056);
  a.Axh2 = (unsigned short*)(ws + 1114112);
  a.A0   = (unsigned short*)(ws + 1671168);
  a.A1   = (unsigned short*)(ws + 1998848);
  a.A2   = (unsigned short*)(ws + 2293760);
  a.fc1t = (unsigned short*)(ws + 2588672);
  a.fc2t = (unsigned short*)(ws + 2658304);
  a.mlvt = (unsigned short*)(ws + 2727936);
  a.g0t  = (unsigned short*)(ws + 2745344);
  a.g1t  = (unsigned short*)(ws + 2755584);
  a.w0b  = (unsigned short*)(ws + 2757632);
  a.w1b  = (unsigned short*)(ws + 3085312);
  a.w2b  = (unsigned short*)(ws + 3380224);
  a.cf   = ws + 3687808;

  dim3 blkP(256), blkG(128);
  k_prep<<<1673, blkP, 0, stream>>>(a);
  pipe32<17, 1, 12, true, false><<<dim3(64, 8), blkG, 0, stream>>>(
      a.Ax, a.fc1t, 256, a.fc1b, nullptr, a.Axh, 544, 267, nullptr);
  pipe32<17, 1, 12, true, false><<<dim3(64, 8), blkG, 0, stream>>>(
      a.Axh, a.fc2t, 256, a.fc2b, nullptr, a.Axh2, 544, 267, nullptr);
  k_mulv_gate<<<128, blkP, 0, stream>>>(a);
  pipe32<10, 8, 12, true, false><<<dim3(64, 8), blkG, 0, stream>>>(
      a.A0, a.w0b, 256, a.b0, a.cf, a.A1, 288, 32, nullptr);
  pipe32<9, 8, 12, true, false><<<dim3(64, 8), blkG, 0, stream>>>(
      a.A1, a.w1b, 256, a.b1, a.cf, a.A2, 288, 32, nullptr);
  pipe32<9, 8, 12, false, true><<<dim3(64, 9), blkG, 0, stream>>>(
      a.A2, a.w2b, 267, a.b2, a.cf, nullptr, 0, 0, a.outY);
}